// Round 10
// baseline (344.693 us; speedup 1.0000x reference)
//
#include <hip/hip_runtime.h>
#include <cstdint>
#include <cstddef>

#define NB    2
#define N1    4096
#define N2    16384
#define CF    64
#define KNN   8
#define SPLIT1 16                 // pass-1 candidate splits
#define NS1   (N1 / SPLIT1)       // 256
#define SPLIT2 4                  // selection-pass candidate splits
#define NS2   (N1 / SPLIT2)       // 1024
#define NQ    (NB * N2)           // 32768 queries

// ---------------------------------------------------------------------------
// kernel 0: transpose feat1 [B,C,N1] -> feat1T [B,N1,C]; pack xyz1/flow float4
// ---------------------------------------------------------------------------
__global__ __launch_bounds__(256, 2) void k_pack(
    const float* __restrict__ xyz1, const float* __restrict__ feat1,
    const float* __restrict__ flow,
    float* __restrict__ feat1T, float4* __restrict__ aux4,
    float4* __restrict__ flow4)
{
    __shared__ float tile[64][65];
    const int b  = blockIdx.y;
    const int n0 = blockIdx.x * 64;
    const int tid = threadIdx.x;
    const int nl = tid & 63, cq = tid >> 6;

#pragma unroll
    for (int r = 0; r < 16; ++r) {
        const int c = r * 4 + cq;
        tile[c][nl] = feat1[((size_t)(b * CF + c)) * N1 + n0 + nl];
    }
    __syncthreads();
#pragma unroll
    for (int r = 0; r < 16; ++r) {
        const int nn = r * 4 + cq;
        feat1T[((size_t)(b * N1 + n0 + nn)) * CF + nl] = tile[nl][nn];
    }
    if (tid < 64) {
        const int n = n0 + tid;
        const float x = xyz1[(b * 3 + 0) * N1 + n];
        const float y = xyz1[(b * 3 + 1) * N1 + n];
        const float z = xyz1[(b * 3 + 2) * N1 + n];
        aux4[b * N1 + n] = make_float4(x, y, z, 0.f);
        const float fx = flow[(b * 3 + 0) * N1 + n];
        const float fy = flow[(b * 3 + 1) * N1 + n];
        const float fz = flow[(b * 3 + 2) * N1 + n];
        flow4[b * N1 + n] = make_float4(fx, fy, fz, 0.f);
    }
}

// min/med3 sorted-8 distance network (no index tracking — 8 VALU ops).
#define DNET(d) do { \
    const float m0_ = fminf(d, d0); \
    const float m1_ = __builtin_amdgcn_fmed3f(d, d0, d1); \
    const float m2_ = __builtin_amdgcn_fmed3f(d, d1, d2); \
    const float m3_ = __builtin_amdgcn_fmed3f(d, d2, d3); \
    const float m4_ = __builtin_amdgcn_fmed3f(d, d3, d4); \
    const float m5_ = __builtin_amdgcn_fmed3f(d, d4, d5); \
    const float m6_ = __builtin_amdgcn_fmed3f(d, d5, d6); \
    const float m7_ = __builtin_amdgcn_fmed3f(d, d6, d7); \
    d0=m0_; d1=m1_; d2=m2_; d3=m3_; d4=m4_; d5=m5_; d6=m6_; d7=m7_; \
} while (0)

// exact reference fp32 distance: d = (q2+t2) - (qt+qt), qt=((qx*tx+qy*ty)+qz*tz)
#define DISTQ(qx_, qy_, qz_, q2_, p_) \
    __fsub_rn(__fadd_rn(q2_, (p_).w), \
        __fadd_rn(__fadd_rn(__fadd_rn(__fmul_rn(qx_, (p_).x), \
                                      __fmul_rn(qy_, (p_).y)), \
                            __fmul_rn(qz_, (p_).z)), \
                  __fadd_rn(__fadd_rn(__fmul_rn(qx_, (p_).x), \
                                      __fmul_rn(qy_, (p_).y)), \
                            __fmul_rn(qz_, (p_).z))))

// NOTE: macro above would duplicate qt computation textually; use a function
// to guarantee the single-rounding structure instead:
__device__ __forceinline__ float distq(float qx, float qy, float qz, float q2,
                                       float4 p) {
    const float qt = __fadd_rn(
        __fadd_rn(__fmul_rn(qx, p.x), __fmul_rn(qy, p.y)),
        __fmul_rn(qz, p.z));
    return __fsub_rn(__fadd_rn(q2, p.w), __fadd_rn(qt, qt));
}

// ---------------------------------------------------------------------------
// kernel 1 (pass 1): per-split 8 smallest DISTANCES only. QPT=2.
// partd layout [sp][q][8] for coalesced k_thr reads.
// ---------------------------------------------------------------------------
__global__ __launch_bounds__(256, 2) void k_knn5(
    const float* __restrict__ xyz1, const float* __restrict__ xyz2,
    float* __restrict__ partd)
{
    __shared__ float4 pts[NS1];  // {x,y,z,t2} — 4 KiB
    const int sp  = blockIdx.y;
    const int tid = threadIdx.x;
    const int qa  = blockIdx.x * 512 + tid;
    const int qb  = qa + 256;
    const int b   = qa >> 14;    // uniform per block (512 | 16384)

    if (tid < NS1) {
        const int jg = sp * NS1 + tid;
        const float x = xyz1[(b * 3 + 0) * N1 + jg];
        const float y = xyz1[(b * 3 + 1) * N1 + jg];
        const float z = xyz1[(b * 3 + 2) * N1 + jg];
        const float t2 = __fadd_rn(__fadd_rn(__fmul_rn(x, x), __fmul_rn(y, y)),
                                   __fmul_rn(z, z));
        pts[tid] = make_float4(x, y, z, t2);
    }
    __syncthreads();

    const int na = qa & (N2 - 1), nb = na + 256;
    const float ax = xyz2[(b * 3 + 0) * N2 + na];
    const float ay = xyz2[(b * 3 + 1) * N2 + na];
    const float az = xyz2[(b * 3 + 2) * N2 + na];
    const float a2 = __fadd_rn(__fadd_rn(__fmul_rn(ax, ax), __fmul_rn(ay, ay)),
                               __fmul_rn(az, az));
    const float cx = xyz2[(b * 3 + 0) * N2 + nb];
    const float cy = xyz2[(b * 3 + 1) * N2 + nb];
    const float cz = xyz2[(b * 3 + 2) * N2 + nb];
    const float c2 = __fadd_rn(__fadd_rn(__fmul_rn(cx, cx), __fmul_rn(cy, cy)),
                               __fmul_rn(cz, cz));

    float Aq0=INFINITY,Aq1=INFINITY,Aq2=INFINITY,Aq3=INFINITY,
          Aq4=INFINITY,Aq5=INFINITY,Aq6=INFINITY,Aq7=INFINITY;
    float Bq0=INFINITY,Bq1=INFINITY,Bq2=INFINITY,Bq3=INFINITY,
          Bq4=INFINITY,Bq5=INFINITY,Bq6=INFINITY,Bq7=INFINITY;

#pragma unroll 4
    for (int j = 0; j < NS1; ++j) {
        const float4 p = pts[j];
        const float dA = distq(ax, ay, az, a2, p);
        const float dB = distq(cx, cy, cz, c2, p);
        {   // query A network
            float d0=Aq0,d1=Aq1,d2=Aq2,d3=Aq3,d4=Aq4,d5=Aq5,d6=Aq6,d7=Aq7;
            DNET(dA);
            Aq0=d0;Aq1=d1;Aq2=d2;Aq3=d3;Aq4=d4;Aq5=d5;Aq6=d6;Aq7=d7;
        }
        {   // query B network
            float d0=Bq0,d1=Bq1,d2=Bq2,d3=Bq3,d4=Bq4,d5=Bq5,d6=Bq6,d7=Bq7;
            DNET(dB);
            Bq0=d0;Bq1=d1;Bq2=d2;Bq3=d3;Bq4=d4;Bq5=d5;Bq6=d6;Bq7=d7;
        }
    }

    {
        float* pd = partd + ((size_t)sp * NQ + qa) * KNN;
        pd[0]=Aq0; pd[1]=Aq1; pd[2]=Aq2; pd[3]=Aq3;
        pd[4]=Aq4; pd[5]=Aq5; pd[6]=Aq6; pd[7]=Aq7;
    }
    {
        float* pd = partd + ((size_t)sp * NQ + qb) * KNN;
        pd[0]=Bq0; pd[1]=Bq1; pd[2]=Bq2; pd[3]=Bq3;
        pd[4]=Bq4; pd[5]=Bq5; pd[6]=Bq6; pd[7]=Bq7;
    }
}

// ---------------------------------------------------------------------------
// kernel 2: per query, merge SPLIT1x8 distances -> thr (= global 8th-smallest)
// and t_need = 8 - #{d < thr} (slots to fill with ties at thr).
// ---------------------------------------------------------------------------
__global__ __launch_bounds__(256, 2) void k_thr(
    const float* __restrict__ partd, float* __restrict__ thr,
    int* __restrict__ tneed)
{
    const int q = blockIdx.x * 256 + threadIdx.x;
    float d0=INFINITY,d1=INFINITY,d2=INFINITY,d3=INFINITY,
          d4=INFINITY,d5=INFINITY,d6=INFINITY,d7=INFINITY;

#pragma unroll
    for (int sp = 0; sp < SPLIT1; ++sp) {
        const float* pd = partd + ((size_t)sp * NQ + q) * KNN;
#pragma unroll
        for (int r = 0; r < KNN; ++r) {
            const float d = pd[r];
            DNET(d);
        }
    }
    const int s = (d0 < d7) + (d1 < d7) + (d2 < d7) + (d3 < d7) +
                  (d4 < d7) + (d5 < d7) + (d6 < d7);
    thr[q]   = d7;
    tneed[q] = 8 - s;
}

// ---------------------------------------------------------------------------
// kernel 3 (pass 2): selection scan. Append idx of every d < thr, and of
// d == thr up to t_need (earliest by index -> exact stable-top_k SET).
// Order within the 8 slots is irrelevant (softmax-weighted sum is
// permutation-invariant). Distances recomputed bit-identically to pass 1.
// selbuf[q][sp]: ints [0..7]=strict idx, [8..15]=tie idx, [16]=cnt, [17]=tcnt.
// ---------------------------------------------------------------------------
__global__ __launch_bounds__(256, 2) void k_sel(
    const float* __restrict__ xyz1, const float* __restrict__ xyz2,
    const float* __restrict__ thr, const int* __restrict__ tneed,
    int* __restrict__ selbuf)
{
    __shared__ float4 pts[NS2];  // 16 KiB
    const int sp  = blockIdx.y;
    const int tid = threadIdx.x;
    const int q   = blockIdx.x * 256 + tid;
    const int b   = q >> 14;     // uniform per block (256 | 16384)

    for (int t = tid; t < NS2; t += 256) {
        const int jg = sp * NS2 + t;
        const float x = xyz1[(b * 3 + 0) * N1 + jg];
        const float y = xyz1[(b * 3 + 1) * N1 + jg];
        const float z = xyz1[(b * 3 + 2) * N1 + jg];
        const float t2 = __fadd_rn(__fadd_rn(__fmul_rn(x, x), __fmul_rn(y, y)),
                                   __fmul_rn(z, z));
        pts[t] = make_float4(x, y, z, t2);
    }
    __syncthreads();

    const int n = q & (N2 - 1);
    const float qx = xyz2[(b * 3 + 0) * N2 + n];
    const float qy = xyz2[(b * 3 + 1) * N2 + n];
    const float qz = xyz2[(b * 3 + 2) * N2 + n];
    const float q2 = __fadd_rn(__fadd_rn(__fmul_rn(qx, qx), __fmul_rn(qy, qy)),
                               __fmul_rn(qz, qz));
    const float thrv = thr[q];
    const int   tn   = tneed[q];

    int* buf = selbuf + ((size_t)q * SPLIT2 + sp) * 20;
    int cnt = 0, tcnt = 0;

#pragma unroll 4
    for (int j = 0; j < NS2; ++j) {
        const float4 p = pts[j];
        const float d = distq(qx, qy, qz, q2, p);
        const bool strict = d < thrv;
        const bool tie    = (d == thrv) && (tcnt < tn);
        if (strict || tie) {              // rare: ~8 hits per lane per scan
            const int slot = strict ? (cnt & 7) : (8 + (tcnt & 7));
            buf[slot] = sp * NS2 + j;
            cnt  += strict ? 1 : 0;
            tcnt += tie ? 1 : 0;
        }
    }
    buf[16] = cnt;
    buf[17] = tcnt;
}

// ---------------------------------------------------------------------------
// kernel 4: compact per-split lists (split order = index order) -> knn_idx.
// All strict entries first, then ties until 8 slots filled.
// ---------------------------------------------------------------------------
__global__ __launch_bounds__(256, 2) void k_compact(
    const int* __restrict__ selbuf, int* __restrict__ knn_idx)
{
    const int q = blockIdx.x * 256 + threadIdx.x;
    int* ko = knn_idx + (size_t)q * KNN;
    int pos = 0;
#pragma unroll
    for (int sp = 0; sp < SPLIT2; ++sp) {
        const int* buf = selbuf + ((size_t)q * SPLIT2 + sp) * 20;
        const int c = min(buf[16], 8);
        for (int i = 0; i < c && pos < 8; ++i) ko[pos++] = buf[i];
    }
#pragma unroll
    for (int sp = 0; sp < SPLIT2; ++sp) {
        const int* buf = selbuf + ((size_t)q * SPLIT2 + sp) * 20;
        const int t = min(buf[17], 8);
        for (int i = 0; i < t && pos < 8; ++i) ko[pos++] = buf[8 + i];
    }
    while (pos < 8) ko[pos++] = 0;   // unreachable safety net
}

// ---------------------------------------------------------------------------
// kernel 5: MLP — unchanged from R9 (4 waves share w1s, DPP layer-2, QPW=8)
// ---------------------------------------------------------------------------
__device__ __forceinline__ float wave_sum_dpp(float x) {
    int t;
    t = __builtin_amdgcn_update_dpp(0, __float_as_int(x), 0x111, 0xF, 0xF, false);
    x += __int_as_float(t);
    t = __builtin_amdgcn_update_dpp(0, __float_as_int(x), 0x112, 0xF, 0xF, false);
    x += __int_as_float(t);
    t = __builtin_amdgcn_update_dpp(0, __float_as_int(x), 0x114, 0xF, 0xF, false);
    x += __int_as_float(t);
    t = __builtin_amdgcn_update_dpp(0, __float_as_int(x), 0x118, 0xF, 0xF, false);
    x += __int_as_float(t);
    t = __builtin_amdgcn_update_dpp(0, __float_as_int(x), 0x142, 0xA, 0xF, false);
    x += __int_as_float(t);
    t = __builtin_amdgcn_update_dpp(0, __float_as_int(x), 0x143, 0xC, 0xF, false);
    x += __int_as_float(t);
    return __int_as_float(__builtin_amdgcn_readlane(__float_as_int(x), 63));
}

#define ACC4(h, wv, iv) \
    h = fmaf((wv).x, (iv).x, h); h = fmaf((wv).y, (iv).y, h); \
    h = fmaf((wv).z, (iv).z, h); h = fmaf((wv).w, (iv).w, h)

#define DOT17(h, ivr) do { \
    ACC4(h, w0,  (ivr)[0]);  ACC4(h, w1,  (ivr)[1]);  ACC4(h, w2,  (ivr)[2]); \
    ACC4(h, w3,  (ivr)[3]);  ACC4(h, w4,  (ivr)[4]);  ACC4(h, w5,  (ivr)[5]); \
    ACC4(h, w6,  (ivr)[6]);  ACC4(h, w7,  (ivr)[7]);  ACC4(h, w8,  (ivr)[8]); \
    ACC4(h, w9,  (ivr)[9]);  ACC4(h, w10, (ivr)[10]); ACC4(h, w11, (ivr)[11]); \
    ACC4(h, w12, (ivr)[12]); ACC4(h, w13, (ivr)[13]); ACC4(h, w14, (ivr)[14]); \
    ACC4(h, w15, (ivr)[15]); ACC4(h, w16, (ivr)[16]); \
} while (0)

#define L2RED(hk, a0, a1, a2) do { \
    float hv_ = (hk); hv_ = hv_ >= 0.f ? hv_ : 0.1f * hv_; \
    a0 = wave_sum_dpp(w2a * hv_) + b20; \
    a1 = wave_sum_dpp(w2b * hv_) + b21; \
    a2 = wave_sum_dpp(w2c * hv_) + b22; \
} while (0)

#define SMAX8(sa, sb, sc, sd, se, sf, sg, sh, CH, res) do { \
    const float m_ = fmaxf(fmaxf(fmaxf(sa, sb), fmaxf(sc, sd)), \
                           fmaxf(fmaxf(se, sf), fmaxf(sg, sh))); \
    const float e0_ = __expf(sa - m_), e1_ = __expf(sb - m_); \
    const float e2_ = __expf(sc - m_), e3_ = __expf(sd - m_); \
    const float e4_ = __expf(se - m_), e5_ = __expf(sf - m_); \
    const float e6_ = __expf(sg - m_), e7_ = __expf(sh - m_); \
    const float S_ = ((e0_ + e1_) + (e2_ + e3_)) + ((e4_ + e5_) + (e6_ + e7_)); \
    float acc_ = e0_ * flf[0 * 4 + CH]; \
    acc_ = fmaf(e1_, flf[1 * 4 + CH], acc_); acc_ = fmaf(e2_, flf[2 * 4 + CH], acc_); \
    acc_ = fmaf(e3_, flf[3 * 4 + CH], acc_); acc_ = fmaf(e4_, flf[4 * 4 + CH], acc_); \
    acc_ = fmaf(e5_, flf[5 * 4 + CH], acc_); acc_ = fmaf(e6_, flf[6 * 4 + CH], acc_); \
    acc_ = fmaf(e7_, flf[7 * 4 + CH], acc_); \
    res = acc_ / S_; \
} while (0)

#define MLP_STEP(IT) do { \
    const int n_ = n0 + (IT); \
    __builtin_amdgcn_wave_barrier(); \
    float4* drow = (float4*)(inw + k * 68); \
    drow[p * 2] = g0; drow[p * 2 + 1] = g1; \
    if (p == 0) { \
        inw[k * 68 + 64] = axv.x - qx; inw[k * 68 + 65] = axv.y - qy; \
        inw[k * 68 + 66] = axv.z - qz; inw[k * 68 + 67] = 0.f; \
    } \
    if (p == 1) flbuf[wave][k] = flv; \
    __builtin_amdgcn_wave_barrier(); \
    if ((IT) < 7) { \
        const int idn_ = idnext; \
        const float4* fr_ = (const float4*)(feat1T + (size_t)(base + idn_) * CF); \
        g0 = fr_[p * 2]; g1 = fr_[p * 2 + 1]; \
        axv = aux4[base + idn_]; flv = flow4[base + idn_]; \
        qx = xyz2[(b * 3 + 0) * N2 + n_ + 1]; \
        qy = xyz2[(b * 3 + 1) * N2 + n_ + 1]; \
        qz = xyz2[(b * 3 + 2) * N2 + n_ + 1]; \
        if ((IT) < 6) idnext = knn_idx[(size_t)(q0 + (IT) + 2) * KNN + k]; \
    } \
    float s00, s01, s02, s03, s04, s05, s06, s07; \
    float s10, s11, s12, s13, s14, s15, s16, s17; \
    float s20, s21, s22, s23, s24, s25, s26, s27; \
    { float h = b1v; DOT17(h, ((const float4*)(inw + 0 * 68))); L2RED(h, s00, s10, s20); } \
    { float h = b1v; DOT17(h, ((const float4*)(inw + 1 * 68))); L2RED(h, s01, s11, s21); } \
    { float h = b1v; DOT17(h, ((const float4*)(inw + 2 * 68))); L2RED(h, s02, s12, s22); } \
    { float h = b1v; DOT17(h, ((const float4*)(inw + 3 * 68))); L2RED(h, s03, s13, s23); } \
    { float h = b1v; DOT17(h, ((const float4*)(inw + 4 * 68))); L2RED(h, s04, s14, s24); } \
    { float h = b1v; DOT17(h, ((const float4*)(inw + 5 * 68))); L2RED(h, s05, s15, s25); } \
    { float h = b1v; DOT17(h, ((const float4*)(inw + 6 * 68))); L2RED(h, s06, s16, s26); } \
    { float h = b1v; DOT17(h, ((const float4*)(inw + 7 * 68))); L2RED(h, s07, s17, s27); } \
    float res0, res1, res2; \
    SMAX8(s00, s01, s02, s03, s04, s05, s06, s07, 0, res0); \
    SMAX8(s10, s11, s12, s13, s14, s15, s16, s17, 1, res1); \
    SMAX8(s20, s21, s22, s23, s24, s25, s26, s27, 2, res2); \
    const float resv = lane == 0 ? res0 : (lane == 1 ? res1 : res2); \
    if (lane < 3) out[((size_t)(b * 3 + lane)) * N2 + n_] = resv; \
} while (0)

__global__ __launch_bounds__(256, 2) void k_mlp4(
    const float* __restrict__ feat1T, const float4* __restrict__ aux4,
    const float4* __restrict__ flow4, const int* __restrict__ knn_idx,
    const float* __restrict__ xyz2,
    const float* __restrict__ W1, const float* __restrict__ b1,
    const float* __restrict__ W2, const float* __restrict__ b2,
    float* __restrict__ out)
{
    __shared__ __align__(16) float w1s[64 * 68];
    __shared__ __align__(16) float inbuf[4][8][68];
    __shared__ __align__(16) float4 flbuf[4][8];

    const int tid  = threadIdx.x;
    const int wave = tid >> 6, lane = tid & 63;

    for (int t = tid; t < 64 * 67; t += 256) {
        const int o = t / 67, c = t - o * 67;
        w1s[o * 68 + c] = W1[t];
    }
    if (tid < 64) w1s[tid * 68 + 67] = 0.f;

    const float b1v = b1[lane];
    const float w2a = W2[lane], w2b = W2[64 + lane], w2c = W2[128 + lane];
    const float b20 = b2[0], b21 = b2[1], b22 = b2[2];
    __syncthreads();

    const float4* wr = (const float4*)&w1s[lane * 68];
    const float4 w0 = wr[0],  w1 = wr[1],  w2 = wr[2],  w3 = wr[3];
    const float4 w4 = wr[4],  w5 = wr[5],  w6 = wr[6],  w7 = wr[7];
    const float4 w8 = wr[8],  w9 = wr[9],  w10 = wr[10], w11 = wr[11];
    const float4 w12 = wr[12], w13 = wr[13], w14 = wr[14], w15 = wr[15];
    const float4 w16 = wr[16];

    const int k = lane >> 3, p = lane & 7;
    float* inw = &inbuf[wave][0][0];
    const float* flf = (const float*)&flbuf[wave][0];

    const int q0   = blockIdx.x * 32 + wave * 8;
    const int b    = q0 >> 14;
    const int base = b * N1;
    const int n0   = q0 & (N2 - 1);

    const int id0v = knn_idx[(size_t)q0 * KNN + k];
    int idnext     = knn_idx[(size_t)(q0 + 1) * KNN + k];

    const float4* fr0 = (const float4*)(feat1T + (size_t)(base + id0v) * CF);
    float4 g0 = fr0[p * 2], g1 = fr0[p * 2 + 1];
    float4 axv = aux4[base + id0v];
    float4 flv = flow4[base + id0v];
    float qx = xyz2[(b * 3 + 0) * N2 + n0];
    float qy = xyz2[(b * 3 + 1) * N2 + n0];
    float qz = xyz2[(b * 3 + 2) * N2 + n0];

    MLP_STEP(0);
    MLP_STEP(1);
    MLP_STEP(2);
    MLP_STEP(3);
    MLP_STEP(4);
    MLP_STEP(5);
    MLP_STEP(6);
    MLP_STEP(7);
}

// ---------------------------------------------------------------------------
extern "C" void kernel_launch(void* const* d_in, const int* in_sizes, int n_in,
                              void* d_out, int out_size, void* d_ws, size_t ws_size,
                              hipStream_t stream)
{
    const float* xyz1  = (const float*)d_in[0];
    const float* xyz2  = (const float*)d_in[1];
    const float* feat1 = (const float*)d_in[2];
    const float* flow  = (const float*)d_in[3];
    const float* W1    = (const float*)d_in[4];
    const float* b1    = (const float*)d_in[5];
    const float* W2    = (const float*)d_in[6];
    const float* b2    = (const float*)d_in[7];
    float* out = (float*)d_out;

    // ws layout (all sizes rounded to 1 MiB):
    //   feat1T   2 MiB   @ 0
    //   aux4   0.5 MiB   @ 2
    //   flow4  0.5 MiB   @ 2.5  -> 3
    //   knn_idx  1 MiB   @ 3
    //   partd   16 MiB   @ 4    (SPLIT1 * 32768 * 8 * 4 B)
    //   thr    0.5 MiB   @ 20
    //   tneed  0.5 MiB   @ 20.5 -> 21
    //   selbuf ~10.5 MiB @ 21   (32768 * 4 * 20 * 4 B)
    // total ~31.5 MiB (< 35.25 MiB proven available in R9)
    char* ws = (char*)d_ws;
    float*  feat1T  = (float*)(ws);
    float4* aux4    = (float4*)(ws + (size_t)(2u << 20));
    float4* flow4   = (float4*)(ws + (size_t)(2u << 20) + (512u << 10));
    int*    knn_idx = (int*)  (ws + (size_t)(3u << 20));
    float*  partd   = (float*)(ws + (size_t)(4u << 20));
    float*  thr     = (float*)(ws + (size_t)(20u << 20));
    int*    tneed   = (int*)  (ws + (size_t)(20u << 20) + (512u << 10));
    int*    selbuf  = (int*)  (ws + (size_t)(21u << 20));

    hipLaunchKernelGGL(k_pack, dim3(N1 / 64, NB), dim3(256), 0, stream,
                       xyz1, feat1, flow, feat1T, aux4, flow4);
    hipLaunchKernelGGL(k_knn5, dim3(NQ / 512, SPLIT1), dim3(256), 0, stream,
                       xyz1, xyz2, partd);
    hipLaunchKernelGGL(k_thr, dim3(NQ / 256), dim3(256), 0, stream,
                       partd, thr, tneed);
    hipLaunchKernelGGL(k_sel, dim3(NQ / 256, SPLIT2), dim3(256), 0, stream,
                       xyz1, xyz2, thr, tneed, selbuf);
    hipLaunchKernelGGL(k_compact, dim3(NQ / 256), dim3(256), 0, stream,
                       selbuf, knn_idx);
    hipLaunchKernelGGL(k_mlp4, dim3(NQ / 32), dim3(256), 0, stream,
                       feat1T, aux4, flow4, knn_idx, xyz2, W1, b1, W2, b2, out);
}

// Round 11
// 318.294 us; speedup vs baseline: 1.0829x; 1.0829x over previous
//
#include <hip/hip_runtime.h>
#include <cstdint>
#include <cstddef>

#define NB    2
#define N1    4096
#define N2    16384
#define CF    64
#define KNN   8

// ---------------------------------------------------------------------------
// Scalarized stable top-8 insert (merge kernel): strict <, descending update
// order reading pre-update values -> lower index wins ties (= top_k).
// ---------------------------------------------------------------------------
#define TKDECL(P) \
    float P##d0=INFINITY,P##d1=INFINITY,P##d2=INFINITY,P##d3=INFINITY, \
          P##d4=INFINITY,P##d5=INFINITY,P##d6=INFINITY,P##d7=INFINITY; \
    int   P##i0=0,P##i1=0,P##i2=0,P##i3=0,P##i4=0,P##i5=0,P##i6=0,P##i7=0

#define TKINS(P, dv, ix) do { \
    const bool c0_ = (dv) < P##d0, c1_ = (dv) < P##d1, c2_ = (dv) < P##d2, c3_ = (dv) < P##d3; \
    const bool c4_ = (dv) < P##d4, c5_ = (dv) < P##d5, c6_ = (dv) < P##d6, c7_ = (dv) < P##d7; \
    P##d7 = c6_ ? P##d6 : (c7_ ? (dv) : P##d7);  P##i7 = c6_ ? P##i6 : (c7_ ? (ix) : P##i7); \
    P##d6 = c5_ ? P##d5 : (c6_ ? (dv) : P##d6);  P##i6 = c5_ ? P##i5 : (c6_ ? (ix) : P##i6); \
    P##d5 = c4_ ? P##d4 : (c5_ ? (dv) : P##d5);  P##i5 = c4_ ? P##i4 : (c5_ ? (ix) : P##i5); \
    P##d4 = c3_ ? P##d3 : (c4_ ? (dv) : P##d4);  P##i4 = c3_ ? P##i3 : (c4_ ? (ix) : P##i4); \
    P##d3 = c2_ ? P##d2 : (c3_ ? (dv) : P##d3);  P##i3 = c2_ ? P##i2 : (c3_ ? (ix) : P##i3); \
    P##d2 = c1_ ? P##d1 : (c2_ ? (dv) : P##d2);  P##i2 = c1_ ? P##i1 : (c2_ ? (ix) : P##i2); \
    P##d1 = c0_ ? P##d0 : (c1_ ? (dv) : P##d1);  P##i1 = c0_ ? P##i0 : (c1_ ? (ix) : P##i1); \
    P##d0 = c0_ ? (dv) : P##d0;                  P##i0 = c0_ ? (ix) : P##i0; \
} while (0)

// ---------------------------------------------------------------------------
// kernel 0: transpose feat1 [B,C,N1] -> feat1T [B,N1,C]; pack xyz1/flow float4
// ---------------------------------------------------------------------------
__global__ __launch_bounds__(256, 2) void k_pack(
    const float* __restrict__ xyz1, const float* __restrict__ feat1,
    const float* __restrict__ flow,
    float* __restrict__ feat1T, float4* __restrict__ aux4,
    float4* __restrict__ flow4)
{
    __shared__ float tile[64][65];
    const int b  = blockIdx.y;
    const int n0 = blockIdx.x * 64;
    const int tid = threadIdx.x;
    const int nl = tid & 63, cq = tid >> 6;

#pragma unroll
    for (int r = 0; r < 16; ++r) {
        const int c = r * 4 + cq;
        tile[c][nl] = feat1[((size_t)(b * CF + c)) * N1 + n0 + nl];
    }
    __syncthreads();
#pragma unroll
    for (int r = 0; r < 16; ++r) {
        const int nn = r * 4 + cq;
        feat1T[((size_t)(b * N1 + n0 + nn)) * CF + nl] = tile[nl][nn];
    }
    if (tid < 64) {
        const int n = n0 + tid;
        const float x = xyz1[(b * 3 + 0) * N1 + n];
        const float y = xyz1[(b * 3 + 1) * N1 + n];
        const float z = xyz1[(b * 3 + 2) * N1 + n];
        aux4[b * N1 + n] = make_float4(x, y, z, 0.f);
        const float fx = flow[(b * 3 + 0) * N1 + n];
        const float fy = flow[(b * 3 + 1) * N1 + n];
        const float fz = flow[(b * 3 + 2) * N1 + n];
        flow4[b * N1 + n] = make_float4(fx, fy, fz, 0.f);
    }
}

// ---------------------------------------------------------------------------
// kernel 1: partial KNN — R9's proven kernel (142 us @ SPLIT=16). QPT=2,
// branchless, med3 distance network, cndmask index network.
// Distance replicates reference fp32 rounding exactly:
// d = (q2+t2) - (qt+qt), qt = ((qx*tx+qy*ty)+qz*tz), all _rn.
// ---------------------------------------------------------------------------
template <int SPLIT_>
__global__ __launch_bounds__(256, 2) void k_knn4t(
    const float* __restrict__ xyz1, const float* __restrict__ xyz2,
    float* __restrict__ partd, int* __restrict__ parti)
{
    constexpr int NS_ = N1 / SPLIT_;
    __shared__ float4 pts[NS_];  // {x, y, z, t2}
    const int sp  = blockIdx.y;
    const int tid = threadIdx.x;
    const int q0  = blockIdx.x * 512 + tid;
    const int q1  = q0 + 256;
    const int b   = q0 >> 14;    // uniform per block (512 | 16384)

    for (int t = tid; t < NS_; t += 256) {
        const int jg = sp * NS_ + t;
        const float x = xyz1[(b * 3 + 0) * N1 + jg];
        const float y = xyz1[(b * 3 + 1) * N1 + jg];
        const float z = xyz1[(b * 3 + 2) * N1 + jg];
        const float t2 = __fadd_rn(__fadd_rn(__fmul_rn(x, x), __fmul_rn(y, y)),
                                   __fmul_rn(z, z));
        pts[t] = make_float4(x, y, z, t2);
    }
    __syncthreads();

    const int n0 = q0 & (N2 - 1), n1 = n0 + 256;
    const float ax = xyz2[(b * 3 + 0) * N2 + n0];
    const float ay = xyz2[(b * 3 + 1) * N2 + n0];
    const float az = xyz2[(b * 3 + 2) * N2 + n0];
    const float a2 = __fadd_rn(__fadd_rn(__fmul_rn(ax, ax), __fmul_rn(ay, ay)),
                               __fmul_rn(az, az));
    const float cx = xyz2[(b * 3 + 0) * N2 + n1];
    const float cy = xyz2[(b * 3 + 1) * N2 + n1];
    const float cz = xyz2[(b * 3 + 2) * N2 + n1];
    const float c2 = __fadd_rn(__fadd_rn(__fmul_rn(cx, cx), __fmul_rn(cy, cy)),
                               __fmul_rn(cz, cz));

    float Ad0=INFINITY,Ad1=INFINITY,Ad2=INFINITY,Ad3=INFINITY,
          Ad4=INFINITY,Ad5=INFINITY,Ad6=INFINITY,Ad7=INFINITY;
    int   Ai0=0,Ai1=0,Ai2=0,Ai3=0,Ai4=0,Ai5=0,Ai6=0,Ai7=0;
    float Bd0=INFINITY,Bd1=INFINITY,Bd2=INFINITY,Bd3=INFINITY,
          Bd4=INFINITY,Bd5=INFINITY,Bd6=INFINITY,Bd7=INFINITY;
    int   Bi0=0,Bi1=0,Bi2=0,Bi3=0,Bi4=0,Bi5=0,Bi6=0,Bi7=0;

#pragma unroll 4
    for (int j = 0; j < NS_; ++j) {
        const float4 p = pts[j];
        const int idx = sp * NS_ + j;

        const float qtA = __fadd_rn(
            __fadd_rn(__fmul_rn(ax, p.x), __fmul_rn(ay, p.y)),
            __fmul_rn(az, p.z));
        const float dA = __fsub_rn(__fadd_rn(a2, p.w), __fadd_rn(qtA, qtA));
        const float qtB = __fadd_rn(
            __fadd_rn(__fmul_rn(cx, p.x), __fmul_rn(cy, p.y)),
            __fmul_rn(cz, p.z));
        const float dB = __fsub_rn(__fadd_rn(c2, p.w), __fadd_rn(qtB, qtB));

        {
            const float m0 = fminf(dA, Ad0);
            const float m1 = __builtin_amdgcn_fmed3f(dA, Ad0, Ad1);
            const float m2 = __builtin_amdgcn_fmed3f(dA, Ad1, Ad2);
            const float m3 = __builtin_amdgcn_fmed3f(dA, Ad2, Ad3);
            const float m4 = __builtin_amdgcn_fmed3f(dA, Ad3, Ad4);
            const float m5 = __builtin_amdgcn_fmed3f(dA, Ad4, Ad5);
            const float m6 = __builtin_amdgcn_fmed3f(dA, Ad5, Ad6);
            const float m7 = __builtin_amdgcn_fmed3f(dA, Ad6, Ad7);
            const bool a0 = dA < Ad0, a1 = dA < Ad1, a2c = dA < Ad2, a3 = dA < Ad3;
            const bool a4 = dA < Ad4, a5 = dA < Ad5, a6 = dA < Ad6, a7 = dA < Ad7;
            Ai7 = a6 ? Ai6 : (a7 ? idx : Ai7);
            Ai6 = a5 ? Ai5 : (a6 ? idx : Ai6);
            Ai5 = a4 ? Ai4 : (a5 ? idx : Ai5);
            Ai4 = a3 ? Ai3 : (a4 ? idx : Ai4);
            Ai3 = a2c ? Ai2 : (a3 ? idx : Ai3);
            Ai2 = a1 ? Ai1 : (a2c ? idx : Ai2);
            Ai1 = a0 ? Ai0 : (a1 ? idx : Ai1);
            Ai0 = a0 ? idx : Ai0;
            Ad0=m0; Ad1=m1; Ad2=m2; Ad3=m3; Ad4=m4; Ad5=m5; Ad6=m6; Ad7=m7;
        }
        {
            const float m0 = fminf(dB, Bd0);
            const float m1 = __builtin_amdgcn_fmed3f(dB, Bd0, Bd1);
            const float m2 = __builtin_amdgcn_fmed3f(dB, Bd1, Bd2);
            const float m3 = __builtin_amdgcn_fmed3f(dB, Bd2, Bd3);
            const float m4 = __builtin_amdgcn_fmed3f(dB, Bd3, Bd4);
            const float m5 = __builtin_amdgcn_fmed3f(dB, Bd4, Bd5);
            const float m6 = __builtin_amdgcn_fmed3f(dB, Bd5, Bd6);
            const float m7 = __builtin_amdgcn_fmed3f(dB, Bd6, Bd7);
            const bool a0 = dB < Bd0, a1 = dB < Bd1, a2c = dB < Bd2, a3 = dB < Bd3;
            const bool a4 = dB < Bd4, a5 = dB < Bd5, a6 = dB < Bd6, a7 = dB < Bd7;
            Bi7 = a6 ? Bi6 : (a7 ? idx : Bi7);
            Bi6 = a5 ? Bi5 : (a6 ? idx : Bi6);
            Bi5 = a4 ? Bi4 : (a5 ? idx : Bi5);
            Bi4 = a3 ? Bi3 : (a4 ? idx : Bi4);
            Bi3 = a2c ? Bi2 : (a3 ? idx : Bi3);
            Bi2 = a1 ? Bi1 : (a2c ? idx : Bi2);
            Bi1 = a0 ? Bi0 : (a1 ? idx : Bi1);
            Bi0 = a0 ? idx : Bi0;
            Bd0=m0; Bd1=m1; Bd2=m2; Bd3=m3; Bd4=m4; Bd5=m5; Bd6=m6; Bd7=m7;
        }
    }

    {
        float* pd = partd + ((size_t)q0 * SPLIT_ + sp) * KNN;
        int*   pi = parti + ((size_t)q0 * SPLIT_ + sp) * KNN;
        pd[0]=Ad0; pd[1]=Ad1; pd[2]=Ad2; pd[3]=Ad3; pd[4]=Ad4; pd[5]=Ad5; pd[6]=Ad6; pd[7]=Ad7;
        pi[0]=Ai0; pi[1]=Ai1; pi[2]=Ai2; pi[3]=Ai3; pi[4]=Ai4; pi[5]=Ai5; pi[6]=Ai6; pi[7]=Ai7;
    }
    {
        float* pd = partd + ((size_t)q1 * SPLIT_ + sp) * KNN;
        int*   pi = parti + ((size_t)q1 * SPLIT_ + sp) * KNN;
        pd[0]=Bd0; pd[1]=Bd1; pd[2]=Bd2; pd[3]=Bd3; pd[4]=Bd4; pd[5]=Bd5; pd[6]=Bd6; pd[7]=Bd7;
        pi[0]=Bi0; pi[1]=Bi1; pi[2]=Bi2; pi[3]=Bi3; pi[4]=Bi4; pi[5]=Bi5; pi[6]=Bi6; pi[7]=Bi7;
    }
}

// ---------------------------------------------------------------------------
// kernel 2: merge SPLIT partial top-8 lists (ascending split order -> stable)
// ---------------------------------------------------------------------------
template <int SPLIT_>
__global__ __launch_bounds__(256, 2) void k_merge2t(
    const float* __restrict__ partd, const int* __restrict__ parti,
    int* __restrict__ knn_idx)
{
    const int q = blockIdx.x * 256 + threadIdx.x;
    const float* pd = partd + (size_t)q * SPLIT_ * KNN;
    const int*   pi = parti + (size_t)q * SPLIT_ * KNN;

    TKDECL(M);
#pragma unroll
    for (int t = 0; t < SPLIT_ * KNN; ++t) {
        const float d = pd[t];
        const int   i = pi[t];
        TKINS(M, d, i);
    }
    int* ko = knn_idx + (size_t)q * KNN;
    ko[0]=Mi0; ko[1]=Mi1; ko[2]=Mi2; ko[3]=Mi3; ko[4]=Mi4; ko[5]=Mi5; ko[6]=Mi6; ko[7]=Mi7;
}

// ---------------------------------------------------------------------------
// kernel 3: MLP v5 — ILP restructure of mlp4 (which stalled at VALUBusy 64%:
// serial 68-FMA accumulator chain + un-hoistable LDS loads). Layer 1 now
// c4-outer / kk-inner in quads of 4: each round issues 4 independent LDS
// loads feeding 4 independent FMA chains (next round's loads hide under this
// round's FMAs). DPP reductions run 12 chains interleaved. FMA order per h
// unchanged -> bit-identical results to mlp4.
// ---------------------------------------------------------------------------
#define R4(WV, C4, BK) { \
    const float4 i0_ = *(const float4*)(inw + ((BK)+0)*68 + (C4)*4); \
    const float4 i1_ = *(const float4*)(inw + ((BK)+1)*68 + (C4)*4); \
    const float4 i2_ = *(const float4*)(inw + ((BK)+2)*68 + (C4)*4); \
    const float4 i3_ = *(const float4*)(inw + ((BK)+3)*68 + (C4)*4); \
    ha = fmaf((WV).x, i0_.x, ha); ha = fmaf((WV).y, i0_.y, ha); \
    ha = fmaf((WV).z, i0_.z, ha); ha = fmaf((WV).w, i0_.w, ha); \
    hb = fmaf((WV).x, i1_.x, hb); hb = fmaf((WV).y, i1_.y, hb); \
    hb = fmaf((WV).z, i1_.z, hb); hb = fmaf((WV).w, i1_.w, hb); \
    hc = fmaf((WV).x, i2_.x, hc); hc = fmaf((WV).y, i2_.y, hc); \
    hc = fmaf((WV).z, i2_.z, hc); hc = fmaf((WV).w, i2_.w, hc); \
    hd = fmaf((WV).x, i3_.x, hd); hd = fmaf((WV).y, i3_.y, hd); \
    hd = fmaf((WV).z, i3_.z, hd); hd = fmaf((WV).w, i3_.w, hd); \
}

#define DPP1(v, CTRL, RM) \
    v += __int_as_float(__builtin_amdgcn_update_dpp( \
        0, __float_as_int(v), CTRL, RM, 0xF, false))

#define DPPALL(CTRL, RM) do { \
    DPP1(pa0,CTRL,RM); DPP1(pb0,CTRL,RM); DPP1(pc0,CTRL,RM); DPP1(pd0,CTRL,RM); \
    DPP1(pa1,CTRL,RM); DPP1(pb1,CTRL,RM); DPP1(pc1,CTRL,RM); DPP1(pd1,CTRL,RM); \
    DPP1(pa2,CTRL,RM); DPP1(pb2,CTRL,RM); DPP1(pc2,CTRL,RM); DPP1(pd2,CTRL,RM); \
} while (0)

#define RDL(v) __int_as_float(__builtin_amdgcn_readlane(__float_as_int(v), 63))

#define L1L2_QUAD(BK, SA0,SA1,SA2,SA3, SB0,SB1,SB2,SB3, SC0,SC1,SC2,SC3) do { \
    float ha = b1v, hb = b1v, hc = b1v, hd = b1v; \
    R4(w0, 0, BK)  R4(w1, 1, BK)  R4(w2, 2, BK)  R4(w3, 3, BK) \
    R4(w4, 4, BK)  R4(w5, 5, BK)  R4(w6, 6, BK)  R4(w7, 7, BK) \
    R4(w8, 8, BK)  R4(w9, 9, BK)  R4(w10,10, BK) R4(w11,11, BK) \
    R4(w12,12, BK) R4(w13,13, BK) R4(w14,14, BK) R4(w15,15, BK) \
    R4(w16,16, BK) \
    ha = ha >= 0.f ? ha : 0.1f * ha; \
    hb = hb >= 0.f ? hb : 0.1f * hb; \
    hc = hc >= 0.f ? hc : 0.1f * hc; \
    hd = hd >= 0.f ? hd : 0.1f * hd; \
    float pa0 = w2a*ha, pb0 = w2a*hb, pc0 = w2a*hc, pd0 = w2a*hd; \
    float pa1 = w2b*ha, pb1 = w2b*hb, pc1 = w2b*hc, pd1 = w2b*hd; \
    float pa2 = w2c*ha, pb2 = w2c*hb, pc2 = w2c*hc, pd2 = w2c*hd; \
    DPPALL(0x111, 0xF); DPPALL(0x112, 0xF); DPPALL(0x114, 0xF); \
    DPPALL(0x118, 0xF); DPPALL(0x142, 0xA); DPPALL(0x143, 0xC); \
    SA0 = RDL(pa0) + b20; SA1 = RDL(pb0) + b20; \
    SA2 = RDL(pc0) + b20; SA3 = RDL(pd0) + b20; \
    SB0 = RDL(pa1) + b21; SB1 = RDL(pb1) + b21; \
    SB2 = RDL(pc1) + b21; SB3 = RDL(pd1) + b21; \
    SC0 = RDL(pa2) + b22; SC1 = RDL(pb2) + b22; \
    SC2 = RDL(pc2) + b22; SC3 = RDL(pd2) + b22; \
} while (0)

#define SMAX8(sa, sb, sc, sd, se, sf, sg, sh, CH, res) do { \
    const float m_ = fmaxf(fmaxf(fmaxf(sa, sb), fmaxf(sc, sd)), \
                           fmaxf(fmaxf(se, sf), fmaxf(sg, sh))); \
    const float e0_ = __expf(sa - m_), e1_ = __expf(sb - m_); \
    const float e2_ = __expf(sc - m_), e3_ = __expf(sd - m_); \
    const float e4_ = __expf(se - m_), e5_ = __expf(sf - m_); \
    const float e6_ = __expf(sg - m_), e7_ = __expf(sh - m_); \
    const float S_ = ((e0_ + e1_) + (e2_ + e3_)) + ((e4_ + e5_) + (e6_ + e7_)); \
    float acc_ = e0_ * flf[0 * 4 + CH]; \
    acc_ = fmaf(e1_, flf[1 * 4 + CH], acc_); acc_ = fmaf(e2_, flf[2 * 4 + CH], acc_); \
    acc_ = fmaf(e3_, flf[3 * 4 + CH], acc_); acc_ = fmaf(e4_, flf[4 * 4 + CH], acc_); \
    acc_ = fmaf(e5_, flf[5 * 4 + CH], acc_); acc_ = fmaf(e6_, flf[6 * 4 + CH], acc_); \
    acc_ = fmaf(e7_, flf[7 * 4 + CH], acc_); \
    res = acc_ / S_; \
} while (0)

#define MLP_STEP(IT) do { \
    const int n_ = n0 + (IT); \
    __builtin_amdgcn_wave_barrier();  /* WAR: prev-iter reads precede writes */ \
    float4* drow = (float4*)(inw + k * 68); \
    drow[p * 2] = g0; drow[p * 2 + 1] = g1; \
    if (p == 0) { \
        inw[k * 68 + 64] = axv.x - qx; inw[k * 68 + 65] = axv.y - qy; \
        inw[k * 68 + 66] = axv.z - qz; inw[k * 68 + 67] = 0.f; \
    } \
    if (p == 1) flbuf[wave][k] = flv; \
    __builtin_amdgcn_wave_barrier();  /* RAW: writes precede this iter's reads */ \
    if ((IT) < 7) {   /* prefetch next query's gather under this compute */ \
        const int idn_ = idnext; \
        const float4* fr_ = (const float4*)(feat1T + (size_t)(base + idn_) * CF); \
        g0 = fr_[p * 2]; g1 = fr_[p * 2 + 1]; \
        axv = aux4[base + idn_]; flv = flow4[base + idn_]; \
        qx = xyz2[(b * 3 + 0) * N2 + n_ + 1]; \
        qy = xyz2[(b * 3 + 1) * N2 + n_ + 1]; \
        qz = xyz2[(b * 3 + 2) * N2 + n_ + 1]; \
        if ((IT) < 6) idnext = knn_idx[(size_t)(q0 + (IT) + 2) * KNN + k]; \
    } \
    float s00, s01, s02, s03, s04, s05, s06, s07; \
    float s10, s11, s12, s13, s14, s15, s16, s17; \
    float s20, s21, s22, s23, s24, s25, s26, s27; \
    L1L2_QUAD(0, s00,s01,s02,s03, s10,s11,s12,s13, s20,s21,s22,s23); \
    L1L2_QUAD(4, s04,s05,s06,s07, s14,s15,s16,s17, s24,s25,s26,s27); \
    float res0, res1, res2; \
    SMAX8(s00, s01, s02, s03, s04, s05, s06, s07, 0, res0); \
    SMAX8(s10, s11, s12, s13, s14, s15, s16, s17, 1, res1); \
    SMAX8(s20, s21, s22, s23, s24, s25, s26, s27, 2, res2); \
    const float resv = lane == 0 ? res0 : (lane == 1 ? res1 : res2); \
    if (lane < 3) out[((size_t)(b * 3 + lane)) * N2 + n_] = resv; \
} while (0)

__global__ __launch_bounds__(256, 2) void k_mlp5(
    const float* __restrict__ feat1T, const float4* __restrict__ aux4,
    const float4* __restrict__ flow4, const int* __restrict__ knn_idx,
    const float* __restrict__ xyz2,
    const float* __restrict__ W1, const float* __restrict__ b1,
    const float* __restrict__ W2, const float* __restrict__ b2,
    float* __restrict__ out)
{
    __shared__ __align__(16) float w1s[64 * 68];     // 17.0 KiB, shared by 4 waves
    __shared__ __align__(16) float inbuf[4][8][68];  //  8.5 KiB, private per wave
    __shared__ __align__(16) float4 flbuf[4][8];     //  0.5 KiB, private per wave

    const int tid  = threadIdx.x;
    const int wave = tid >> 6, lane = tid & 63;

    for (int t = tid; t < 64 * 67; t += 256) {
        const int o = t / 67, c = t - o * 67;
        w1s[o * 68 + c] = W1[t];
    }
    if (tid < 64) w1s[tid * 68 + 67] = 0.f;

    const float b1v = b1[lane];
    const float w2a = W2[lane], w2b = W2[64 + lane], w2c = W2[128 + lane];
    const float b20 = b2[0], b21 = b2[1], b22 = b2[2];
    __syncthreads();   // the ONLY cross-wave barrier

    const float4* wr = (const float4*)&w1s[lane * 68];
    const float4 w0 = wr[0],  w1 = wr[1],  w2 = wr[2],  w3 = wr[3];
    const float4 w4 = wr[4],  w5 = wr[5],  w6 = wr[6],  w7 = wr[7];
    const float4 w8 = wr[8],  w9 = wr[9],  w10 = wr[10], w11 = wr[11];
    const float4 w12 = wr[12], w13 = wr[13], w14 = wr[14], w15 = wr[15];
    const float4 w16 = wr[16];

    const int k = lane >> 3, p = lane & 7;
    float* inw = &inbuf[wave][0][0];
    const float* flf = (const float*)&flbuf[wave][0];

    const int q0   = blockIdx.x * 32 + wave * 8;   // 8 queries per wave
    const int b    = q0 >> 14;                      // uniform (32 | 16384)
    const int base = b * N1;
    const int n0   = q0 & (N2 - 1);

    const int id0v = knn_idx[(size_t)q0 * KNN + k];
    int idnext     = knn_idx[(size_t)(q0 + 1) * KNN + k];

    const float4* fr0 = (const float4*)(feat1T + (size_t)(base + id0v) * CF);
    float4 g0 = fr0[p * 2], g1 = fr0[p * 2 + 1];
    float4 axv = aux4[base + id0v];
    float4 flv = flow4[base + id0v];
    float qx = xyz2[(b * 3 + 0) * N2 + n0];
    float qy = xyz2[(b * 3 + 1) * N2 + n0];
    float qz = xyz2[(b * 3 + 2) * N2 + n0];

    MLP_STEP(0);
    MLP_STEP(1);
    MLP_STEP(2);
    MLP_STEP(3);
    MLP_STEP(4);
    MLP_STEP(5);
    MLP_STEP(6);
    MLP_STEP(7);
}

// ---------------------------------------------------------------------------
extern "C" void kernel_launch(void* const* d_in, const int* in_sizes, int n_in,
                              void* d_out, int out_size, void* d_ws, size_t ws_size,
                              hipStream_t stream)
{
    const float* xyz1  = (const float*)d_in[0];
    const float* xyz2  = (const float*)d_in[1];
    const float* feat1 = (const float*)d_in[2];
    const float* flow  = (const float*)d_in[3];
    const float* W1    = (const float*)d_in[4];
    const float* b1    = (const float*)d_in[5];
    const float* W2    = (const float*)d_in[6];
    const float* b2    = (const float*)d_in[7];
    float* out = (float*)d_out;

    char* ws = (char*)d_ws;
    float*  feat1T  = (float*)(ws);                                   // 2 MiB
    float4* aux4    = (float4*)(ws + (2u << 20));                     // 128 KiB
    float4* flow4   = (float4*)(ws + (2u << 20) + (128u << 10));      // 128 KiB
    int*    knn_idx = (int*)  (ws + (2u << 20) + (256u << 10));       // 1 MiB
    char*   part0   = ws + (3u << 20) + (256u << 10);

    // SPLIT=16 needs 3.25 + 2*16 = 35.25 MiB of ws; fall back to SPLIT=8.
    const size_t need16 = (size_t)(3u << 20) + (256u << 10) + 2 * (size_t)(16u << 20);

    hipLaunchKernelGGL(k_pack, dim3(N1 / 64, NB), dim3(256), 0, stream,
                       xyz1, feat1, flow, feat1T, aux4, flow4);

    if (ws_size >= need16) {
        float* partd = (float*)part0;
        int*   parti = (int*)(part0 + (size_t)(16u << 20));
        hipLaunchKernelGGL((k_knn4t<16>), dim3(NB * N2 / 512, 16), dim3(256),
                           0, stream, xyz1, xyz2, partd, parti);
        hipLaunchKernelGGL((k_merge2t<16>), dim3(NB * N2 / 256), dim3(256),
                           0, stream, partd, parti, knn_idx);
    } else {
        float* partd = (float*)part0;
        int*   parti = (int*)(part0 + (size_t)(8u << 20));
        hipLaunchKernelGGL((k_knn4t<8>), dim3(NB * N2 / 512, 8), dim3(256),
                           0, stream, xyz1, xyz2, partd, parti);
        hipLaunchKernelGGL((k_merge2t<8>), dim3(NB * N2 / 256), dim3(256),
                           0, stream, partd, parti, knn_idx);
    }

    hipLaunchKernelGGL(k_mlp5, dim3(NB * N2 / 32), dim3(256), 0, stream,
                       feat1T, aux4, flow4, knn_idx, xyz2, W1, b1, W2, b2, out);
}

// Round 13
// 291.226 us; speedup vs baseline: 1.1836x; 1.0929x over previous
//
#include <hip/hip_runtime.h>
#include <cstdint>
#include <cstddef>

#define NB    2
#define N1    4096
#define N2    16384
#define CF    64
#define KNN   8
#define SPLIT1 16                 // pass-1 splits
#define NS1   (N1 / SPLIT1)       // 256 candidates per split
#define NQ    (NB * N2)           // 32768 queries

// min/med3 sorted-8 distance network (no index tracking — 8 VALU ops).
#define DNET(d) do { \
    const float m0_ = fminf(d, d0); \
    const float m1_ = __builtin_amdgcn_fmed3f(d, d0, d1); \
    const float m2_ = __builtin_amdgcn_fmed3f(d, d1, d2); \
    const float m3_ = __builtin_amdgcn_fmed3f(d, d2, d3); \
    const float m4_ = __builtin_amdgcn_fmed3f(d, d3, d4); \
    const float m5_ = __builtin_amdgcn_fmed3f(d, d4, d5); \
    const float m6_ = __builtin_amdgcn_fmed3f(d, d5, d6); \
    const float m7_ = __builtin_amdgcn_fmed3f(d, d6, d7); \
    d0=m0_; d1=m1_; d2=m2_; d3=m3_; d4=m4_; d5=m5_; d6=m6_; d7=m7_; \
} while (0)

// exact reference fp32 distance: d = (q2+t2) - (qt+qt), qt=((qx*tx+qy*ty)+qz*tz)
__device__ __forceinline__ float distq(float qx, float qy, float qz, float q2,
                                       float4 p) {
    const float qt = __fadd_rn(
        __fadd_rn(__fmul_rn(qx, p.x), __fmul_rn(qy, p.y)),
        __fmul_rn(qz, p.z));
    return __fsub_rn(__fadd_rn(q2, p.w), __fadd_rn(qt, qt));
}

// ---------------------------------------------------------------------------
// kernel 0: transpose feat1 [B,C,N1] -> feat1T [B,N1,C]; pack xyz1/flow float4
// ---------------------------------------------------------------------------
__global__ __launch_bounds__(256, 2) void k_pack(
    const float* __restrict__ xyz1, const float* __restrict__ feat1,
    const float* __restrict__ flow,
    float* __restrict__ feat1T, float4* __restrict__ aux4,
    float4* __restrict__ flow4)
{
    __shared__ float tile[64][65];
    const int b  = blockIdx.y;
    const int n0 = blockIdx.x * 64;
    const int tid = threadIdx.x;
    const int nl = tid & 63, cq = tid >> 6;

#pragma unroll
    for (int r = 0; r < 16; ++r) {
        const int c = r * 4 + cq;
        tile[c][nl] = feat1[((size_t)(b * CF + c)) * N1 + n0 + nl];
    }
    __syncthreads();
#pragma unroll
    for (int r = 0; r < 16; ++r) {
        const int nn = r * 4 + cq;
        feat1T[((size_t)(b * N1 + n0 + nn)) * CF + nl] = tile[nl][nn];
    }
    if (tid < 64) {
        const int n = n0 + tid;
        const float x = xyz1[(b * 3 + 0) * N1 + n];
        const float y = xyz1[(b * 3 + 1) * N1 + n];
        const float z = xyz1[(b * 3 + 2) * N1 + n];
        aux4[b * N1 + n] = make_float4(x, y, z, 0.f);
        const float fx = flow[(b * 3 + 0) * N1 + n];
        const float fy = flow[(b * 3 + 1) * N1 + n];
        const float fz = flow[(b * 3 + 2) * N1 + n];
        flow4[b * N1 + n] = make_float4(fx, fy, fz, 0.f);
    }
}

// ---------------------------------------------------------------------------
// kernel 1 (pass 1, R10-proven): per-split 8 smallest DISTANCES. QPT=2.
// No index tracking, no compares — pure min/med3 chain. Layout [sp][q][8].
// ---------------------------------------------------------------------------
__global__ __launch_bounds__(256, 2) void k_knn5(
    const float* __restrict__ xyz1, const float* __restrict__ xyz2,
    float* __restrict__ partd)
{
    __shared__ float4 pts[NS1];  // {x,y,z,t2} — 4 KiB
    const int sp  = blockIdx.y;
    const int tid = threadIdx.x;
    const int qa  = blockIdx.x * 512 + tid;
    const int qb  = qa + 256;
    const int b   = qa >> 14;    // uniform per block (512 | 16384)

    if (tid < NS1) {
        const int jg = sp * NS1 + tid;
        const float x = xyz1[(b * 3 + 0) * N1 + jg];
        const float y = xyz1[(b * 3 + 1) * N1 + jg];
        const float z = xyz1[(b * 3 + 2) * N1 + jg];
        const float t2 = __fadd_rn(__fadd_rn(__fmul_rn(x, x), __fmul_rn(y, y)),
                                   __fmul_rn(z, z));
        pts[tid] = make_float4(x, y, z, t2);
    }
    __syncthreads();

    const int na = qa & (N2 - 1), nb = na + 256;
    const float ax = xyz2[(b * 3 + 0) * N2 + na];
    const float ay = xyz2[(b * 3 + 1) * N2 + na];
    const float az = xyz2[(b * 3 + 2) * N2 + na];
    const float a2 = __fadd_rn(__fadd_rn(__fmul_rn(ax, ax), __fmul_rn(ay, ay)),
                               __fmul_rn(az, az));
    const float cx = xyz2[(b * 3 + 0) * N2 + nb];
    const float cy = xyz2[(b * 3 + 1) * N2 + nb];
    const float cz = xyz2[(b * 3 + 2) * N2 + nb];
    const float c2 = __fadd_rn(__fadd_rn(__fmul_rn(cx, cx), __fmul_rn(cy, cy)),
                               __fmul_rn(cz, cz));

    float Aq0=INFINITY,Aq1=INFINITY,Aq2=INFINITY,Aq3=INFINITY,
          Aq4=INFINITY,Aq5=INFINITY,Aq6=INFINITY,Aq7=INFINITY;
    float Bq0=INFINITY,Bq1=INFINITY,Bq2=INFINITY,Bq3=INFINITY,
          Bq4=INFINITY,Bq5=INFINITY,Bq6=INFINITY,Bq7=INFINITY;

#pragma unroll 4
    for (int j = 0; j < NS1; ++j) {
        const float4 p = pts[j];
        const float dA = distq(ax, ay, az, a2, p);
        const float dB = distq(cx, cy, cz, c2, p);
        {
            float d0=Aq0,d1=Aq1,d2=Aq2,d3=Aq3,d4=Aq4,d5=Aq5,d6=Aq6,d7=Aq7;
            DNET(dA);
            Aq0=d0;Aq1=d1;Aq2=d2;Aq3=d3;Aq4=d4;Aq5=d5;Aq6=d6;Aq7=d7;
        }
        {
            float d0=Bq0,d1=Bq1,d2=Bq2,d3=Bq3,d4=Bq4,d5=Bq5,d6=Bq6,d7=Bq7;
            DNET(dB);
            Bq0=d0;Bq1=d1;Bq2=d2;Bq3=d3;Bq4=d4;Bq5=d5;Bq6=d6;Bq7=d7;
        }
    }

    {
        float* pd = partd + ((size_t)sp * NQ + qa) * KNN;
        pd[0]=Aq0; pd[1]=Aq1; pd[2]=Aq2; pd[3]=Aq3;
        pd[4]=Aq4; pd[5]=Aq5; pd[6]=Aq6; pd[7]=Aq7;
    }
    {
        float* pd = partd + ((size_t)sp * NQ + qb) * KNN;
        pd[0]=Bq0; pd[1]=Bq1; pd[2]=Bq2; pd[3]=Bq3;
        pd[4]=Bq4; pd[5]=Bq5; pd[6]=Bq6; pd[7]=Bq7;
    }
}

// ---------------------------------------------------------------------------
// kernel 2 (R10-proven): merge SPLIT1x8 distances -> thr = exact global 8th-
// smallest value, tneed = 8 - #{d < thr}.
// ---------------------------------------------------------------------------
__global__ __launch_bounds__(256, 2) void k_thr(
    const float* __restrict__ partd, float* __restrict__ thr,
    int* __restrict__ tneed)
{
    const int q = blockIdx.x * 256 + threadIdx.x;
    float d0=INFINITY,d1=INFINITY,d2=INFINITY,d3=INFINITY,
          d4=INFINITY,d5=INFINITY,d6=INFINITY,d7=INFINITY;

#pragma unroll
    for (int sp = 0; sp < SPLIT1; ++sp) {
        const float* pd = partd + ((size_t)sp * NQ + q) * KNN;
#pragma unroll
        for (int r = 0; r < KNN; ++r) {
            const float d = pd[r];
            DNET(d);
        }
    }
    const int s = (d0 < d7) + (d1 < d7) + (d2 < d7) + (d3 < d7) +
                  (d4 < d7) + (d5 < d7) + (d6 < d7);
    thr[q]   = d7;
    tneed[q] = 8 - s;
}

// ---------------------------------------------------------------------------
// kernel 3 (pass 2): wave-per-query ballot selection with EXACT threshold.
// Strict hits (d < thr): exactly 8-tneed globally (sorted positions 8+ are
// >= thr, so strict count <= 7 — hard bound). Ties (d == thr): accepted
// while tcnt < tneed, in ascending-index arrival order (wave scans chunks /
// t / bits in index order). Total accepted = exactly 8 -> write directly to
// knn_idx; no lists, no capacity risk. Extraction loops are wave-uniform
// SALU (ctz) — no per-lane loop-carried chains (R10's k_sel failure mode).
// ---------------------------------------------------------------------------
__global__ __launch_bounds__(256, 2) void k_sel4(
    const float* __restrict__ xyz1, const float* __restrict__ xyz2,
    const float* __restrict__ thr, const int* __restrict__ tneed,
    int* __restrict__ knn_idx)
{
    __shared__ float4 pts[1024];        // 16 KiB chunk
    const int tid  = threadIdx.x;
    const int wave = tid >> 6, lane = tid & 63;
    const int qbase = blockIdx.x * 8;   // 8 queries per block
    const int b     = qbase >> 14;      // uniform (8 | 16384)

    const int qA = qbase + wave, qB = qA + 4;
    const int nA = qA & (N2 - 1), nB = qB & (N2 - 1);

    const float axA = xyz2[(b * 3 + 0) * N2 + nA];
    const float ayA = xyz2[(b * 3 + 1) * N2 + nA];
    const float azA = xyz2[(b * 3 + 2) * N2 + nA];
    const float a2A = __fadd_rn(__fadd_rn(__fmul_rn(axA, axA), __fmul_rn(ayA, ayA)),
                                __fmul_rn(azA, azA));
    const float axB = xyz2[(b * 3 + 0) * N2 + nB];
    const float ayB = xyz2[(b * 3 + 1) * N2 + nB];
    const float azB = xyz2[(b * 3 + 2) * N2 + nB];
    const float a2B = __fadd_rn(__fadd_rn(__fmul_rn(axB, axB), __fmul_rn(ayB, ayB)),
                                __fmul_rn(azB, azB));

    const float thrA = thr[qA],  thrB = thr[qB];
    const int   tnA  = tneed[qA], tnB = tneed[qB];

    int posA = 0, posB = 0, tcA = 0, tcB = 0;
    int* koA = knn_idx + (size_t)qA * KNN;
    int* koB = knn_idx + (size_t)qB * KNN;

    for (int c = 0; c < 4; ++c) {
        __syncthreads();   // WAR: previous chunk fully consumed
        for (int t = tid; t < 1024; t += 256) {
            const int jg = c * 1024 + t;
            const float x = xyz1[(b * 3 + 0) * N1 + jg];
            const float y = xyz1[(b * 3 + 1) * N1 + jg];
            const float z = xyz1[(b * 3 + 2) * N1 + jg];
            const float t2 = __fadd_rn(
                __fadd_rn(__fmul_rn(x, x), __fmul_rn(y, y)), __fmul_rn(z, z));
            pts[t] = make_float4(x, y, z, t2);
        }
        __syncthreads();

        for (int t = 0; t < 16; ++t) {
            const float4 p = pts[t * 64 + lane];
            const float dA = distq(axA, ayA, azA, a2A, p);
            const float dB = distq(axB, ayB, azB, a2B, p);
            unsigned long long sA = __ballot(dA <  thrA);
            unsigned long long eA = __ballot(dA == thrA);
            unsigned long long sB = __ballot(dB <  thrB);
            unsigned long long eB = __ballot(dB == thrB);
            const int jbase = c * 1024 + t * 64;
            while (sA) {   // strict hits: all accepted (<= 7 total, exact)
                const int bit = __builtin_ctzll(sA); sA &= sA - 1;
                if (lane == 0 && posA < 8) koA[posA] = jbase + bit;
                ++posA;
            }
            while (eA && tcA < tnA) {   // ties: first tneed in index order
                const int bit = __builtin_ctzll(eA); eA &= eA - 1;
                if (lane == 0 && posA < 8) koA[posA] = jbase + bit;
                ++posA; ++tcA;
            }
            while (sB) {
                const int bit = __builtin_ctzll(sB); sB &= sB - 1;
                if (lane == 0 && posB < 8) koB[posB] = jbase + bit;
                ++posB;
            }
            while (eB && tcB < tnB) {
                const int bit = __builtin_ctzll(eB); eB &= eB - 1;
                if (lane == 0 && posB < 8) koB[posB] = jbase + bit;
                ++posB; ++tcB;
            }
        }
    }
}

// ---------------------------------------------------------------------------
// kernel 4: MLP v5 — unchanged from R11 (proven: 4 waves share w1s, quad-ILP
// layer 1, interleaved DPP reductions, QPW=8, launch_bounds(256,2)).
// ---------------------------------------------------------------------------
#define R4(WV, C4, BK) { \
    const float4 i0_ = *(const float4*)(inw + ((BK)+0)*68 + (C4)*4); \
    const float4 i1_ = *(const float4*)(inw + ((BK)+1)*68 + (C4)*4); \
    const float4 i2_ = *(const float4*)(inw + ((BK)+2)*68 + (C4)*4); \
    const float4 i3_ = *(const float4*)(inw + ((BK)+3)*68 + (C4)*4); \
    ha = fmaf((WV).x, i0_.x, ha); ha = fmaf((WV).y, i0_.y, ha); \
    ha = fmaf((WV).z, i0_.z, ha); ha = fmaf((WV).w, i0_.w, ha); \
    hb = fmaf((WV).x, i1_.x, hb); hb = fmaf((WV).y, i1_.y, hb); \
    hb = fmaf((WV).z, i1_.z, hb); hb = fmaf((WV).w, i1_.w, hb); \
    hc = fmaf((WV).x, i2_.x, hc); hc = fmaf((WV).y, i2_.y, hc); \
    hc = fmaf((WV).z, i2_.z, hc); hc = fmaf((WV).w, i2_.w, hc); \
    hd = fmaf((WV).x, i3_.x, hd); hd = fmaf((WV).y, i3_.y, hd); \
    hd = fmaf((WV).z, i3_.z, hd); hd = fmaf((WV).w, i3_.w, hd); \
}

#define DPP1(v, CTRL, RM) \
    v += __int_as_float(__builtin_amdgcn_update_dpp( \
        0, __float_as_int(v), CTRL, RM, 0xF, false))

#define DPPALL(CTRL, RM) do { \
    DPP1(pa0,CTRL,RM); DPP1(pb0,CTRL,RM); DPP1(pc0,CTRL,RM); DPP1(pd0,CTRL,RM); \
    DPP1(pa1,CTRL,RM); DPP1(pb1,CTRL,RM); DPP1(pc1,CTRL,RM); DPP1(pd1,CTRL,RM); \
    DPP1(pa2,CTRL,RM); DPP1(pb2,CTRL,RM); DPP1(pc2,CTRL,RM); DPP1(pd2,CTRL,RM); \
} while (0)

#define RDL(v) __int_as_float(__builtin_amdgcn_readlane(__float_as_int(v), 63))

#define L1L2_QUAD(BK, SA0,SA1,SA2,SA3, SB0,SB1,SB2,SB3, SC0,SC1,SC2,SC3) do { \
    float ha = b1v, hb = b1v, hc = b1v, hd = b1v; \
    R4(w0, 0, BK)  R4(w1, 1, BK)  R4(w2, 2, BK)  R4(w3, 3, BK) \
    R4(w4, 4, BK)  R4(w5, 5, BK)  R4(w6, 6, BK)  R4(w7, 7, BK) \
    R4(w8, 8, BK)  R4(w9, 9, BK)  R4(w10,10, BK) R4(w11,11, BK) \
    R4(w12,12, BK) R4(w13,13, BK) R4(w14,14, BK) R4(w15,15, BK) \
    R4(w16,16, BK) \
    ha = ha >= 0.f ? ha : 0.1f * ha; \
    hb = hb >= 0.f ? hb : 0.1f * hb; \
    hc = hc >= 0.f ? hc : 0.1f * hc; \
    hd = hd >= 0.f ? hd : 0.1f * hd; \
    float pa0 = w2a*ha, pb0 = w2a*hb, pc0 = w2a*hc, pd0 = w2a*hd; \
    float pa1 = w2b*ha, pb1 = w2b*hb, pc1 = w2b*hc, pd1 = w2b*hd; \
    float pa2 = w2c*ha, pb2 = w2c*hb, pc2 = w2c*hc, pd2 = w2c*hd; \
    DPPALL(0x111, 0xF); DPPALL(0x112, 0xF); DPPALL(0x114, 0xF); \
    DPPALL(0x118, 0xF); DPPALL(0x142, 0xA); DPPALL(0x143, 0xC); \
    SA0 = RDL(pa0) + b20; SA1 = RDL(pb0) + b20; \
    SA2 = RDL(pc0) + b20; SA3 = RDL(pd0) + b20; \
    SB0 = RDL(pa1) + b21; SB1 = RDL(pb1) + b21; \
    SB2 = RDL(pc1) + b21; SB3 = RDL(pd1) + b21; \
    SC0 = RDL(pa2) + b22; SC1 = RDL(pb2) + b22; \
    SC2 = RDL(pc2) + b22; SC3 = RDL(pd2) + b22; \
} while (0)

#define SMAX8(sa, sb, sc, sd, se, sf, sg, sh, CH, res) do { \
    const float m_ = fmaxf(fmaxf(fmaxf(sa, sb), fmaxf(sc, sd)), \
                           fmaxf(fmaxf(se, sf), fmaxf(sg, sh))); \
    const float e0_ = __expf(sa - m_), e1_ = __expf(sb - m_); \
    const float e2_ = __expf(sc - m_), e3_ = __expf(sd - m_); \
    const float e4_ = __expf(se - m_), e5_ = __expf(sf - m_); \
    const float e6_ = __expf(sg - m_), e7_ = __expf(sh - m_); \
    const float S_ = ((e0_ + e1_) + (e2_ + e3_)) + ((e4_ + e5_) + (e6_ + e7_)); \
    float acc_ = e0_ * flf[0 * 4 + CH]; \
    acc_ = fmaf(e1_, flf[1 * 4 + CH], acc_); acc_ = fmaf(e2_, flf[2 * 4 + CH], acc_); \
    acc_ = fmaf(e3_, flf[3 * 4 + CH], acc_); acc_ = fmaf(e4_, flf[4 * 4 + CH], acc_); \
    acc_ = fmaf(e5_, flf[5 * 4 + CH], acc_); acc_ = fmaf(e6_, flf[6 * 4 + CH], acc_); \
    acc_ = fmaf(e7_, flf[7 * 4 + CH], acc_); \
    res = acc_ / S_; \
} while (0)

#define MLP_STEP(IT) do { \
    const int n_ = n0 + (IT); \
    __builtin_amdgcn_wave_barrier(); \
    float4* drow = (float4*)(inw + k * 68); \
    drow[p * 2] = g0; drow[p * 2 + 1] = g1; \
    if (p == 0) { \
        inw[k * 68 + 64] = axv.x - qx; inw[k * 68 + 65] = axv.y - qy; \
        inw[k * 68 + 66] = axv.z - qz; inw[k * 68 + 67] = 0.f; \
    } \
    if (p == 1) flbuf[wave][k] = flv; \
    __builtin_amdgcn_wave_barrier(); \
    if ((IT) < 7) { \
        const int idn_ = idnext; \
        const float4* fr_ = (const float4*)(feat1T + (size_t)(base + idn_) * CF); \
        g0 = fr_[p * 2]; g1 = fr_[p * 2 + 1]; \
        axv = aux4[base + idn_]; flv = flow4[base + idn_]; \
        qx = xyz2[(b * 3 + 0) * N2 + n_ + 1]; \
        qy = xyz2[(b * 3 + 1) * N2 + n_ + 1]; \
        qz = xyz2[(b * 3 + 2) * N2 + n_ + 1]; \
        if ((IT) < 6) idnext = knn_idx[(size_t)(q0 + (IT) + 2) * KNN + k]; \
    } \
    float s00, s01, s02, s03, s04, s05, s06, s07; \
    float s10, s11, s12, s13, s14, s15, s16, s17; \
    float s20, s21, s22, s23, s24, s25, s26, s27; \
    L1L2_QUAD(0, s00,s01,s02,s03, s10,s11,s12,s13, s20,s21,s22,s23); \
    L1L2_QUAD(4, s04,s05,s06,s07, s14,s15,s16,s17, s24,s25,s26,s27); \
    float res0, res1, res2; \
    SMAX8(s00, s01, s02, s03, s04, s05, s06, s07, 0, res0); \
    SMAX8(s10, s11, s12, s13, s14, s15, s16, s17, 1, res1); \
    SMAX8(s20, s21, s22, s23, s24, s25, s26, s27, 2, res2); \
    const float resv = lane == 0 ? res0 : (lane == 1 ? res1 : res2); \
    if (lane < 3) out[((size_t)(b * 3 + lane)) * N2 + n_] = resv; \
} while (0)

__global__ __launch_bounds__(256, 2) void k_mlp5(
    const float* __restrict__ feat1T, const float4* __restrict__ aux4,
    const float4* __restrict__ flow4, const int* __restrict__ knn_idx,
    const float* __restrict__ xyz2,
    const float* __restrict__ W1, const float* __restrict__ b1,
    const float* __restrict__ W2, const float* __restrict__ b2,
    float* __restrict__ out)
{
    __shared__ __align__(16) float w1s[64 * 68];
    __shared__ __align__(16) float inbuf[4][8][68];
    __shared__ __align__(16) float4 flbuf[4][8];

    const int tid  = threadIdx.x;
    const int wave = tid >> 6, lane = tid & 63;

    for (int t = tid; t < 64 * 67; t += 256) {
        const int o = t / 67, c = t - o * 67;
        w1s[o * 68 + c] = W1[t];
    }
    if (tid < 64) w1s[tid * 68 + 67] = 0.f;

    const float b1v = b1[lane];
    const float w2a = W2[lane], w2b = W2[64 + lane], w2c = W2[128 + lane];
    const float b20 = b2[0], b21 = b2[1], b22 = b2[2];
    __syncthreads();

    const float4* wr = (const float4*)&w1s[lane * 68];
    const float4 w0 = wr[0],  w1 = wr[1],  w2 = wr[2],  w3 = wr[3];
    const float4 w4 = wr[4],  w5 = wr[5],  w6 = wr[6],  w7 = wr[7];
    const float4 w8 = wr[8],  w9 = wr[9],  w10 = wr[10], w11 = wr[11];
    const float4 w12 = wr[12], w13 = wr[13], w14 = wr[14], w15 = wr[15];
    const float4 w16 = wr[16];

    const int k = lane >> 3, p = lane & 7;
    float* inw = &inbuf[wave][0][0];
    const float* flf = (const float*)&flbuf[wave][0];

    const int q0   = blockIdx.x * 32 + wave * 8;
    const int b    = q0 >> 14;
    const int base = b * N1;
    const int n0   = q0 & (N2 - 1);

    const int id0v = knn_idx[(size_t)q0 * KNN + k];
    int idnext     = knn_idx[(size_t)(q0 + 1) * KNN + k];

    const float4* fr0 = (const float4*)(feat1T + (size_t)(base + id0v) * CF);
    float4 g0 = fr0[p * 2], g1 = fr0[p * 2 + 1];
    float4 axv = aux4[base + id0v];
    float4 flv = flow4[base + id0v];
    float qx = xyz2[(b * 3 + 0) * N2 + n0];
    float qy = xyz2[(b * 3 + 1) * N2 + n0];
    float qz = xyz2[(b * 3 + 2) * N2 + n0];

    MLP_STEP(0);
    MLP_STEP(1);
    MLP_STEP(2);
    MLP_STEP(3);
    MLP_STEP(4);
    MLP_STEP(5);
    MLP_STEP(6);
    MLP_STEP(7);
}

// ---------------------------------------------------------------------------
extern "C" void kernel_launch(void* const* d_in, const int* in_sizes, int n_in,
                              void* d_out, int out_size, void* d_ws, size_t ws_size,
                              hipStream_t stream)
{
    const float* xyz1  = (const float*)d_in[0];
    const float* xyz2  = (const float*)d_in[1];
    const float* feat1 = (const float*)d_in[2];
    const float* flow  = (const float*)d_in[3];
    const float* W1    = (const float*)d_in[4];
    const float* b1    = (const float*)d_in[5];
    const float* W2    = (const float*)d_in[6];
    const float* b2    = (const float*)d_in[7];
    float* out = (float*)d_out;

    // ws layout: feat1T 2M @0 | aux4 .5M @2M | flow4 .5M @2.5M |
    //            knn_idx 1M @3M | partd 16M @4M | thr .5M @20M |
    //            tneed .5M @20.5M    (total 21 MiB; 35.25 proven in R9)
    char* ws = (char*)d_ws;
    float*  feat1T  = (float*)(ws);
    float4* aux4    = (float4*)(ws + (size_t)(2u << 20));
    float4* flow4   = (float4*)(ws + (size_t)(2u << 20) + (512u << 10));
    int*    knn_idx = (int*)  (ws + (size_t)(3u << 20));
    float*  partd   = (float*)(ws + (size_t)(4u << 20));
    float*  thr     = (float*)(ws + (size_t)(20u << 20));
    int*    tneed   = (int*)  (ws + (size_t)(20u << 20) + (512u << 10));

    hipLaunchKernelGGL(k_pack, dim3(N1 / 64, NB), dim3(256), 0, stream,
                       xyz1, feat1, flow, feat1T, aux4, flow4);
    hipLaunchKernelGGL(k_knn5, dim3(NQ / 512, SPLIT1), dim3(256), 0, stream,
                       xyz1, xyz2, partd);
    hipLaunchKernelGGL(k_thr, dim3(NQ / 256), dim3(256), 0, stream,
                       partd, thr, tneed);
    hipLaunchKernelGGL(k_sel4, dim3(NQ / 8), dim3(256), 0, stream,
                       xyz1, xyz2, thr, tneed, knn_idx);
    hipLaunchKernelGGL(k_mlp5, dim3(NQ / 32), dim3(256), 0, stream,
                       feat1T, aux4, flow4, knn_idx, xyz2, W1, b1, W2, b2, out);
}